// Round 4
// baseline (1166.763 us; speedup 1.0000x reference)
//
#include <hip/hip_runtime.h>
#include <cstdint>
#include <cstddef>

#define LOG2E 1.4426950408889634f

__device__ __forceinline__ float fexp2(float x) {
#if __has_builtin(__builtin_amdgcn_exp2f)
  return __builtin_amdgcn_exp2f(x);
#else
  return exp2f(x);
#endif
}

__device__ __forceinline__ float frcp(float x) {
#if __has_builtin(__builtin_amdgcn_rcpf)
  return __builtin_amdgcn_rcpf(x);
#else
  return 1.0f / x;
#endif
}

// broadcast lane l's value of v to all lanes via SGPR
__device__ __forceinline__ float rl(float v, int l) {
  return __int_as_float(__builtin_amdgcn_readlane(__float_as_int(v), l));
}

// DPP move: x from lane per CTRL (within 16-lane row). VALU latency, no LDS.
template <int CTRL>
__device__ __forceinline__ float dppmov(float x) {
  return __int_as_float(
      __builtin_amdgcn_update_dpp(0, __float_as_int(x), CTRL, 0xf, 0xf, true));
}
#define DPP_QUAD_XOR1 0xB1  // quad_perm [1,0,3,2]
#define DPP_QUAD_XOR2 0x4E  // quad_perm [2,3,0,1]
#define DPP_HALF_MIRR 0x141 // row_half_mirror
#define DPP_MIRR 0x140      // row_mirror
// row_ror:N -> lane i receives from lane (i-N)&15 (data rotates toward
// higher lanes; same direction as row_shr per GCN ISA / LLVM scan usage).
#define DPP_ROR1 0x121
#define DPP_ROR4 0x124
#define DPP_ROR8 0x128
#define DPP_ROR12 0x12C

// permlane swap two-output trick: feed x to both operands; the two outputs
// at lane l are {x[l], x[l^16]} (16-swap) or {x[l], x[l^32]} (32-swap) in
// SOME order. A commutative combine (sum/product) is therefore robust to
// the swap-direction semantics.
__device__ __forceinline__ float sum16(float x) {  // x + x(lane^16)
#if __has_builtin(__builtin_amdgcn_permlane16_swap)
  auto r = __builtin_amdgcn_permlane16_swap(__float_as_uint(x),
                                            __float_as_uint(x), false, false);
  return __uint_as_float(r[0]) + __uint_as_float(r[1]);
#else
  float a = x, b = x;
  asm("v_permlane16_swap_b32 %0, %1" : "+v"(a), "+v"(b));
  return a + b;
#endif
}
__device__ __forceinline__ float sum32(float x) {  // x + x(lane^32)
#if __has_builtin(__builtin_amdgcn_permlane32_swap)
  auto r = __builtin_amdgcn_permlane32_swap(__float_as_uint(x),
                                            __float_as_uint(x), false, false);
  return __uint_as_float(r[0]) + __uint_as_float(r[1]);
#else
  float a = x, b = x;
  asm("v_permlane32_swap_b32 %0, %1" : "+v"(a), "+v"(b));
  return a + b;
#endif
}
__device__ __forceinline__ float mul32(float x) {  // x * x(lane^32)
#if __has_builtin(__builtin_amdgcn_permlane32_swap)
  auto r = __builtin_amdgcn_permlane32_swap(__float_as_uint(x),
                                            __float_as_uint(x), false, false);
  return __uint_as_float(r[0]) * __uint_as_float(r[1]);
#else
  float a = x, b = x;
  asm("v_permlane32_swap_b32 %0, %1" : "+v"(a), "+v"(b));
  return a * b;
#endif
}

// One wave (64 lanes) per batch element.
// Lane k owns gate row k of W_hh (k: 0-15 = i, 16-31 = f, 32-47 = g, 48-63 = o).
// Weights prescaled by -log2e (or -2log2e for g) so sigmoid/tanh use raw v_exp_f32.
// No LDS anywhere: cross-lane via permlane16/32_swap + DPP only.
__global__ __launch_bounds__(64) void lstm_gen_kernel(
    const float* __restrict__ x, const float* __restrict__ h0,
    const float* __restrict__ c0, const float* __restrict__ W_ih,
    const float* __restrict__ W_hh, const float* __restrict__ b_ih,
    const float* __restrict__ b_hh, const float* __restrict__ W1,
    const float* __restrict__ b1, const float* __restrict__ W2,
    const float* __restrict__ b2, float* __restrict__ out, int T) {
  const int b = blockIdx.x;
  const int lane = threadIdx.x;      // 0..63
  const int j = lane & 15;           // hidden index within gate block
  const int type = lane >> 4;        // 0 i, 1 f, 2 g, 3 o
  const bool rowodd = (lane & 16) != 0;   // rows 1,3 (f,o)
  const bool isF = (type == 1);
  const bool isO = (type == 3);

  const float sk = (type == 2) ? (-2.0f * LOG2E) : (-LOG2E);
  const float Aact = (type == 2) ? 2.0f : 1.0f;
  const float Bact = (type == 2) ? -1.0f : 0.0f;

  // recurrent weights, prescaled, 16 VGPRs
  float w[16];
#pragma unroll
  for (int jj = 0; jj < 16; ++jj) w[jj] = W_hh[lane * 16 + jj] * sk;
  const float wi = W_ih[lane] * sk;
  const float bk = (b_ih[lane] + b_hh[lane]) * sk;

  // MLP W1 in rotation order: after r right-rotations (row_ror) lane j holds
  // h[(j - r) & 15], so pair it with W1[j][(j - r) & 15].
  float w1rot[16];
#pragma unroll
  for (int r = 0; r < 16; ++r) w1rot[r] = W1[j * 16 + ((j - r) & 15)];
  const float b1r = b1[j];
  const float w2r = W2[j];
  const float b2v = b2[0];

  // replicated state: every lane keeps h[j], c[j] for its j = lane&15
  float h = h0[b * 16 + j];
  float c = c0[b * 16 + j];

  const float* xrow = x + (size_t)b * (size_t)T;
  float* orow = out + (size_t)b * (size_t)T;
  const int T4 = T >> 2;
  const float4* xrow4 = (const float4*)xrow;

  // 3-deep register prefetch pipeline for x
  float4 xa = xrow4[0];
  float4 xb = xrow4[(1 < T4) ? 1 : 0];
  float4 xc2 = xrow4[(2 < T4) ? 2 : 0];

#pragma unroll 1
  for (int t4i = 0; t4i < T4; ++t4i) {
    const float4 xcur = xa;
    xa = xb;
    xb = xc2;
    int nidx = t4i + 3;
    nidx = (nidx < T4) ? nidx : (T4 - 1);
    xc2 = xrow4[nidx];

    float hq = 0.0f;  // row q latches h of sub-step q for the MLP head

#pragma unroll
    for (int tt = 0; tt < 4; ++tt) {
      const float xv = (tt == 0) ? xcur.x : (tt == 1) ? xcur.y
                        : (tt == 2) ? xcur.z : xcur.w;
      // gate_k = sk*( W_ih[k]*x + b_ih[k]+b_hh[k] + sum_j W_hh[k][j]*h[j] )
      float a0 = fmaf(wi, xv, bk);
      float a1 = 0.0f, a2 = 0.0f, a3 = 0.0f;
#pragma unroll
      for (int jj = 0; jj < 16; jj += 4) {
        a0 = fmaf(rl(h, jj + 0), w[jj + 0], a0);
        a1 = fmaf(rl(h, jj + 1), w[jj + 1], a1);
        a2 = fmaf(rl(h, jj + 2), w[jj + 2], a2);
        a3 = fmaf(rl(h, jj + 3), w[jj + 3], a3);
      }
      const float gacc = (a0 + a1) + (a2 + a3);
      // i,f,o: sigmoid = rcp(1+2^gacc); g: tanh = 2*rcp(1+2^gacc)-1
      const float act = fmaf(Aact, frcp(1.0f + fexp2(gacc)), Bact);
      // act per row: r0=sigma(i_j), r1=sigma(f_j), r2=tanh(g_j), r3=sigma(o_j)

      // IG = sigma(i)*tanh(g): lane^32 product puts it at rows 0,2 (col j)
      const float m = mul32(act);                    // rows0,2: IG; rows1,3: F*O
      const float IG_all = sum16(rowodd ? 0.0f : m); // all rows: IG_j
      // F: only row1 has it in act -> mask, row-pair sum, half sum
      const float F_all = sum32(sum16(isF ? act : 0.0f));
      // O: only row3
      const float O_all = sum32(sum16(isO ? act : 0.0f));

      c = fmaf(F_all, c, IG_all);
      // tanh(c) = 1 - 2*rcp(1 + 2^(2*log2e*c))
      const float tc = fmaf(-2.0f, frcp(1.0f + fexp2(c * (2.0f * LOG2E))), 1.0f);
      h = O_all * tc;
      hq = (type == tt) ? h : hq;   // latch for batched MLP head (no LDS)
    }

    // MLP head, batched over 4 timesteps: row q computes step t4i*4+q.
    // y2[j] = b1[j] + sum_l relu(h_l) * W1[j][l] via DPP row_ror systolic matvec
    // (4 parallel rotation chains seeded at ror 0/4/8/12).
    const float cur = fmaxf(hq, 0.0f);
    float r0v = cur;                       // holds h[(j - r) & 15] at step r
    float r4v = dppmov<DPP_ROR4>(cur);     // h[(j - 4 - r) & 15]
    float r8v = dppmov<DPP_ROR8>(cur);     // h[(j - 8 - r) & 15]
    float r12v = dppmov<DPP_ROR12>(cur);   // h[(j - 12 - r) & 15]
    float m0 = fmaf(r0v, w1rot[0], b1r);
    float m1 = r4v * w1rot[4];
    float m2 = r8v * w1rot[8];
    float m3 = r12v * w1rot[12];
#pragma unroll
    for (int r = 1; r < 4; ++r) {
      r0v = dppmov<DPP_ROR1>(r0v);
      r4v = dppmov<DPP_ROR1>(r4v);
      r8v = dppmov<DPP_ROR1>(r8v);
      r12v = dppmov<DPP_ROR1>(r12v);
      m0 = fmaf(r0v, w1rot[r], m0);
      m1 = fmaf(r4v, w1rot[4 + r], m1);
      m2 = fmaf(r8v, w1rot[8 + r], m2);
      m3 = fmaf(r12v, w1rot[12 + r], m3);
    }
    const float y2 = (m0 + m1) + (m2 + m3);

    // z = b2 + sum_j relu(y2_j) * W2[j]: 16-lane reduce via involution DPP adds
    // (quad xor1/xor2, then half_mirror/mirror — valid given quad uniformity).
    float v = fmaxf(y2, 0.0f) * w2r;
    v += dppmov<DPP_QUAD_XOR1>(v);
    v += dppmov<DPP_QUAD_XOR2>(v);
    v += dppmov<DPP_HALF_MIRR>(v);
    v += dppmov<DPP_MIRR>(v);
    const float z = v + b2v;
    // tanh(z)
    const float y3 = fmaf(-2.0f, frcp(1.0f + fexp2(z * (2.0f * LOG2E))), 1.0f);

    if (j == 0) orow[t4i * 4 + type] = y3;  // lanes 0,16,32,48: 4 consecutive
  }
}

extern "C" void kernel_launch(void* const* d_in, const int* in_sizes, int n_in,
                              void* d_out, int out_size, void* d_ws,
                              size_t ws_size, hipStream_t stream) {
  (void)n_in; (void)d_ws; (void)ws_size;
  const float* x = (const float*)d_in[0];
  const float* h0 = (const float*)d_in[1];
  const float* c0 = (const float*)d_in[2];
  const float* W_ih = (const float*)d_in[3];
  const float* W_hh = (const float*)d_in[4];
  const float* b_ih = (const float*)d_in[5];
  const float* b_hh = (const float*)d_in[6];
  const float* W1 = (const float*)d_in[7];
  const float* b1 = (const float*)d_in[8];
  const float* W2 = (const float*)d_in[9];
  const float* b2 = (const float*)d_in[10];

  const int B = in_sizes[1] / 16;           // h0 is [B,16]
  const int T = in_sizes[0] / (B > 0 ? B : 1);

  lstm_gen_kernel<<<B, 64, 0, stream>>>(x, h0, c0, W_ih, W_hh, b_ih, b_hh,
                                        W1, b1, W2, b2, (float*)d_out, T);
}